// Round 6
// baseline (100.306 us; speedup 1.0000x reference)
//
#include <hip/hip_runtime.h>
#include <math.h>

#define TWO_N 512
#define DM    256
#define NT    256

// ws layout (bytes):
//   R     : [512*512] float @ 0         -- distances, natural (row, col) order
//   ts    : [512] float     @ 1048576   -- targets sorted ascending (stable)
//   perm  : [512] int       @ 1050624   -- perm[m] = original index at sorted pos m
//   inv   : [512] int       @ 1052672   -- inv[c]  = sorted position of target c
//   bsums : [512] double    @ 1054720
//   count : uint            @ 1058816
#define OFF_TS   1048576
#define OFF_PERM 1050624
#define OFF_INV  1052672
#define OFF_BSUM 1054720
#define OFF_CNT  1058816

#define ACC4(acc, A, B) { float _d;                      \
    _d = (A).x - (B).x; acc += _d * _d;                  \
    _d = (A).y - (B).y; acc += _d * _d;                  \
    _d = (A).z - (B).z; acc += _d * _d;                  \
    _d = (A).w - (B).w; acc += _d * _d; }

// Blocks 0..255: 32x32 distance tiles, coalesced reads AND writes.
// Block 256: rank-count sort of targets -> ts/perm/inv; zeroes count.
__global__ __launch_bounds__(NT) void supcr_dist_sort(
    const float* __restrict__ E, const float* __restrict__ T,
    float* __restrict__ R, float* __restrict__ ts_g,
    int* __restrict__ perm_g, int* __restrict__ inv_g,
    unsigned int* __restrict__ count)
{
    const int bid = blockIdx.x;
    const int t   = threadIdx.x;

    if (bid < 256) {
        __shared__ float4 As4[32 * 65];   // padded rows: bank-friendly
        __shared__ float4 Bs4[32 * 65];
        const int it = bid >> 4, jt = bid & 15;
        const float4* __restrict__ E4 = reinterpret_cast<const float4*>(E);

        for (int idx = t; idx < 32 * 64; idx += NT) {    // coalesced staging
            const int row = idx >> 6, c4 = idx & 63;
            As4[row * 65 + c4] = E4[(it * 32 + row) * 64 + c4];
            Bs4[row * 65 + c4] = E4[(jt * 32 + row) * 64 + c4];
        }
        __syncthreads();

        const int ty = t >> 4, tx = t & 15;
        float a00 = 0.f, a01 = 0.f, a10 = 0.f, a11 = 0.f;
        #pragma unroll 8
        for (int k4 = 0; k4 < 64; ++k4) {
            const float4 a0 = As4[ty * 65 + k4];
            const float4 a1 = As4[(ty + 16) * 65 + k4];
            const float4 b0 = Bs4[tx * 65 + k4];
            const float4 b1 = Bs4[(tx + 16) * 65 + k4];
            ACC4(a00, a0, b0); ACC4(a01, a0, b1);
            ACC4(a10, a1, b0); ACC4(a11, a1, b1);
        }
        const int r0 = it * 32 + ty, r1 = r0 + 16;
        const int c0 = jt * 32 + tx, c1 = c0 + 16;
        R[r0 * TWO_N + c0] = sqrtf(a00);
        R[r0 * TWO_N + c1] = sqrtf(a01);
        R[r1 * TWO_N + c0] = sqrtf(a10);
        R[r1 * TWO_N + c1] = sqrtf(a11);
    } else {
        // rank-count sort of 512 targets (2 elems/thread), bit-stable ties
        __shared__ float tv[TWO_N];
        tv[t]       = T[t];
        tv[t + 256] = T[t + 256];
        __syncthreads();
        #pragma unroll
        for (int w = 0; w < 2; ++w) {
            const int c  = t + w * 256;
            const float tc = tv[c];
            int r = 0;
            #pragma unroll 8
            for (int j = 0; j < TWO_N; ++j) {
                const float tj = tv[j];
                r += (tj < tc) || (tj == tc && j < c);
            }
            ts_g[r]   = tc;
            perm_g[r] = c;
            inv_g[c]  = r;
        }
        if (t == 0) *count = 0u;
    }
}

// One block per row i. Gather s~ into sorted order, prefix-sum, per-k monotone
// searches give the contiguous {d < theta} interval. Last finished block
// reduces bsums and writes the output (deterministic: fixed tree order).
__global__ __launch_bounds__(NT) void supcr_rows(
    const float* __restrict__ T, const float* __restrict__ R,
    const float* __restrict__ ts_g, const int* __restrict__ perm_g,
    const int* __restrict__ inv_g, double* __restrict__ bsums,
    unsigned int* __restrict__ count, float* __restrict__ out)
{
    const int i = blockIdx.x;
    const int t = threadIdx.x;

    __shared__ float  ts[TWO_N];
    __shared__ float  P[TWO_N];     // inclusive prefix sums of s~ (sorted order)
    __shared__ double red[NT];
    __shared__ bool   last;

    const int   mi = inv_g[i];
    const float ti = T[i];
    const float* __restrict__ row = R + (size_t)i * TWO_N;

    #pragma unroll
    for (int w = 0; w < 2; ++w) {
        const int m = t + w * 256;
        ts[m] = ts_g[m];
        const int pj = perm_g[m];
        P[m] = (pj == i) ? 0.f : __expf(-row[pj]);   // gather (2KB row, L1-hot)
    }
    __syncthreads();

    // inclusive prefix sum (Hillis-Steele), 2 elements/thread
    for (int off = 1; off < TWO_N; off <<= 1) {
        const float v0 = (t >= off)       ? P[t - off]       : 0.f;
        const float v1 = (t + 256 >= off) ? P[t + 256 - off] : 0.f;
        __syncthreads();
        P[t]       += v0;
        P[t + 256] += v1;
        __syncthreads();
    }

    const float Stot = P[TWO_N - 1];

    float local = 0.f;
    #pragma unroll
    for (int w = 0; w < 2; ++w) {
        const int k = t + w * 256;   // ORIGINAL index; coalesced row read
        if (k == i) continue;
        const float theta = fabsf(ti - T[k]);
        const float rik   = row[k];

        // left arm [0, mi]: d non-increasing; count leading d >= theta
        const int nl = mi + 1;
        int pos = 0;
        #pragma unroll
        for (int step = 512; step >= 1; step >>= 1) {
            const int np = pos + step;
            if (np <= nl && fabsf(ti - ts[np - 1]) >= theta) pos = np;
        }
        const int cl = nl - pos;             // left-arm count with d < theta

        // right arm [mi, 511]: d non-decreasing; count leading d < theta
        const int nr = TWO_N - mi;
        int pr = 0;
        #pragma unroll
        for (int step = 512; step >= 1; step >>= 1) {
            const int np = pr + step;
            if (np <= nr && fabsf(ti - ts[mi + np - 1]) < theta) pr = np;
        }

        const int L  = mi - cl + 1;
        const int Rr = mi + pr - 1;
        float inner = 0.f;
        if (Rr >= L) inner = P[Rr] - ((L > 0) ? P[L - 1] : 0.f);
        const float denom = Stot - inner;    // = sum over {d >= theta, j != i}
        local += -rik - logf(denom);
    }

    red[t] = (double)local;
    __syncthreads();
    for (int off = NT / 2; off > 0; off >>= 1) {
        if (t < off) red[t] += red[t + off];
        __syncthreads();
    }

    if (t == 0) {
        __hip_atomic_store(&bsums[i], red[0], __ATOMIC_RELAXED,
                           __HIP_MEMORY_SCOPE_AGENT);
        __threadfence();                              // release
        const unsigned int done = atomicAdd(count, 1u);
        __threadfence();                              // acquire (full fence)
        last = (done == TWO_N - 1);
    }
    __syncthreads();

    if (last) {
        double v0 = __hip_atomic_load(&bsums[t], __ATOMIC_ACQUIRE,
                                      __HIP_MEMORY_SCOPE_AGENT);
        double v1 = __hip_atomic_load(&bsums[t + 256], __ATOMIC_ACQUIRE,
                                      __HIP_MEMORY_SCOPE_AGENT);
        red[t] = v0 + v1;
        __syncthreads();
        for (int off = NT / 2; off > 0; off >>= 1) {
            if (t < off) red[t] += red[t + off];
            __syncthreads();
        }
        if (t == 0)
            out[0] = (float)(-red[0] /
                             (double)((long long)TWO_N * (TWO_N - 1)));
    }
}

extern "C" void kernel_launch(void* const* d_in, const int* in_sizes, int n_in,
                              void* d_out, int out_size, void* d_ws, size_t ws_size,
                              hipStream_t stream) {
    (void)in_sizes; (void)n_in; (void)out_size; (void)ws_size;
    const float* E = (const float*)d_in[0];   // [512,256] fp32
    const float* T = (const float*)d_in[1];   // [512]     fp32
    float* out = (float*)d_out;

    char* ws = (char*)d_ws;
    float*        R      = (float*)(ws);
    float*        ts_g   = (float*)(ws + OFF_TS);
    int*          perm_g = (int*)(ws + OFF_PERM);
    int*          inv_g  = (int*)(ws + OFF_INV);
    double*       bsums  = (double*)(ws + OFF_BSUM);
    unsigned int* cnt    = (unsigned int*)(ws + OFF_CNT);

    supcr_dist_sort<<<257, NT, 0, stream>>>(E, T, R, ts_g, perm_g, inv_g, cnt);
    supcr_rows<<<TWO_N, NT, 0, stream>>>(T, R, ts_g, perm_g, inv_g, bsums, cnt, out);
}